// Round 6
// baseline (1556.828 us; speedup 1.0000x reference)
//
#include <hip/hip_runtime.h>
#include <hip/hip_bf16.h>

typedef __hip_bfloat16 bf16;
typedef short s16x8 __attribute__((ext_vector_type(8)));
typedef float fx4 __attribute__((ext_vector_type(4)));
typedef unsigned int u32;

#define DIM 4096
#define SEQ 2048
#define NH 32
#define HD 128

#define MFMA_BF16(a,b,c) __builtin_amdgcn_mfma_f32_16x16x32_bf16((a),(b),(c),0,0,0)

__device__ __forceinline__ void gload16(const bf16* g, const bf16* l) {
  __builtin_amdgcn_global_load_lds((const __attribute__((address_space(1))) u32*)g,
                                   (__attribute__((address_space(3))) u32*)l, 16, 0, 0);
}

// ---------------- fp32 -> bf16 bulk convert ----------------
__global__ void cvt_f32_bf16(const float* __restrict__ in, bf16* __restrict__ out, int n8)
{
  int i = blockIdx.x * blockDim.x + threadIdx.x;
  const int stride = gridDim.x * blockDim.x;
  for (; i < n8; i += stride) {
    fx4 a = ((const fx4*)in)[2 * i], b = ((const fx4*)in)[2 * i + 1];
    s16x8 o; bf16* op = (bf16*)&o;
    #pragma unroll
    for (int j = 0; j < 4; ++j) { op[j] = __float2bfloat16(a[j]); op[4 + j] = __float2bfloat16(b[j]); }
    ((s16x8*)out)[i] = o;
  }
}

// ---------------- fast GEMM (m97 structure, 128x128 tile) ----------------
// mode 0/1: +RoPE -> (b,h,s,d) bf16
// mode 2:   -> (b,h,d,s) bf16  (V stored TRANSPOSED for attention)
// mode 3:   -> row-major fp32 (d_out)
__global__ __launch_bounds__(256, 2)
void gemm_fast(const bf16* __restrict__ A, const bf16* __restrict__ W,
               const float* __restrict__ bias,
               const float* __restrict__ fcos, const float* __restrict__ fsin,
               void* __restrict__ outv, int mode)
{
  __shared__ __align__(16) bf16 As[128 * 64];
  __shared__ __align__(16) bf16 Bs[128 * 64];
  const int tid = threadIdx.x;
  const int wid = tid >> 6;
  const int lane = tid & 63;
  const int l15 = lane & 15, lg = lane >> 4;
  const int wr = wid >> 1, wc = wid & 1;
  const int brow = blockIdx.y * 128, bcol = blockIdx.x * 128;

  fx4 acc[4][4] = {};

  for (int k0 = 0; k0 < DIM; k0 += 64) {
    #pragma unroll
    for (int i = 0; i < 4; ++i) {
      const int chunk = i * 4 + wid;
      const int row = chunk * 8 + (lane >> 3);
      const int eo = (lane & 7) * 8;
      gload16(A + (size_t)(brow + row) * DIM + k0 + eo, As + chunk * 512);
      gload16(W + (size_t)(bcol + row) * DIM + k0 + eo, Bs + chunk * 512);
    }
    __syncthreads();
    #pragma unroll
    for (int kk = 0; kk < 2; ++kk) {
      s16x8 af[4], bfr[4];
      #pragma unroll
      for (int mi = 0; mi < 4; ++mi)
        af[mi] = *(const s16x8*)&As[(wr * 64 + mi * 16 + l15) * 64 + kk * 32 + lg * 8];
      #pragma unroll
      for (int nj = 0; nj < 4; ++nj)
        bfr[nj] = *(const s16x8*)&Bs[(wc * 64 + nj * 16 + l15) * 64 + kk * 32 + lg * 8];
      #pragma unroll
      for (int mi = 0; mi < 4; ++mi)
        #pragma unroll
        for (int nj = 0; nj < 4; ++nj)
          acc[mi][nj] = MFMA_BF16(af[mi], bfr[nj], acc[mi][nj]);
    }
    __syncthreads();
  }

  #pragma unroll
  for (int mi = 0; mi < 4; ++mi) {
    const int mbase = brow + wr * 64 + mi * 16 + lg * 4;
    #pragma unroll
    for (int nj = 0; nj < 4; ++nj) {
      const int n = bcol + wc * 64 + nj * 16 + l15;
      const float bv = bias[n];
      #pragma unroll
      for (int r = 0; r < 4; ++r) {
        const int m = mbase + r;
        float val = acc[mi][nj][r] + bv;
        if (mode <= 1) {
          const float pv = __shfl_xor(val, 1);
          const int sp = m & (SEQ - 1);
          const int fi = (n >> 1) & 63;
          const float c = fcos[sp * 64 + fi];
          const float s = fsin[sp * 64 + fi];
          val = (n & 1) ? (pv * s + val * c) : (val * c - pv * s);
        }
        if (mode == 3) {
          ((float*)outv)[(size_t)m * DIM + n] = val;
        } else if (mode == 2) {
          const int b = m >> 11, sp = m & (SEQ - 1);
          const int h = n >> 7, d = n & (HD - 1);
          ((bf16*)outv)[((size_t)(b * NH + h) * HD + d) * SEQ + sp] = __float2bfloat16(val);
        } else {
          const int b = m >> 11, sp = m & (SEQ - 1);
          const int h = n >> 7, d = n & (HD - 1);
          ((bf16*)outv)[((size_t)(b * NH + h) * SEQ + sp) * HD + d] = __float2bfloat16(val);
        }
      }
    }
  }
}

// ---------------- slow fallback GEMM (fp32 inputs, reg-staged) ----------------
__global__ __launch_bounds__(256, 2)
void gemm_slow(const void* __restrict__ Av, const float* __restrict__ Wf,
               const float* __restrict__ bias,
               const float* __restrict__ fcos, const float* __restrict__ fsin,
               void* __restrict__ outv, int mode)
{
  __shared__ __align__(16) bf16 As[128 * 64];
  __shared__ __align__(16) bf16 Bs[128 * 64];
  const int abf = (mode == 3) ? 1 : 0;
  const int tid = threadIdx.x;
  const int wid = tid >> 6;
  const int lane = tid & 63;
  const int l15 = lane & 15, lg = lane >> 4;
  const int wr = wid >> 1, wc = wid & 1;
  const int brow = blockIdx.y * 128, bcol = blockIdx.x * 128;

  fx4 acc[4][4] = {};

  for (int k0 = 0; k0 < DIM; k0 += 64) {
    #pragma unroll
    for (int i = 0; i < 4; ++i) {
      const int v = i * 256 + tid;
      const int row = v >> 3;
      const int c8 = (v & 7) * 8;
      s16x8 a, b;
      if (abf) {
        a = *(const s16x8*)&((const bf16*)Av)[(size_t)(brow + row) * DIM + k0 + c8];
      } else {
        const float* Af = (const float*)Av;
        fx4 a0 = *(const fx4*)&Af[(size_t)(brow + row) * DIM + k0 + c8];
        fx4 a1 = *(const fx4*)&Af[(size_t)(brow + row) * DIM + k0 + c8 + 4];
        bf16* ap = (bf16*)&a;
        #pragma unroll
        for (int j = 0; j < 4; ++j) { ap[j] = __float2bfloat16(a0[j]); ap[4 + j] = __float2bfloat16(a1[j]); }
      }
      {
        fx4 b0 = *(const fx4*)&Wf[(size_t)(bcol + row) * DIM + k0 + c8];
        fx4 b1 = *(const fx4*)&Wf[(size_t)(bcol + row) * DIM + k0 + c8 + 4];
        bf16* bp = (bf16*)&b;
        #pragma unroll
        for (int j = 0; j < 4; ++j) { bp[j] = __float2bfloat16(b0[j]); bp[4 + j] = __float2bfloat16(b1[j]); }
      }
      *(s16x8*)&As[row * 64 + c8] = a;
      *(s16x8*)&Bs[row * 64 + c8] = b;
    }
    __syncthreads();
    #pragma unroll
    for (int kk = 0; kk < 2; ++kk) {
      s16x8 af[4], bfr[4];
      #pragma unroll
      for (int mi = 0; mi < 4; ++mi)
        af[mi] = *(const s16x8*)&As[(wr * 64 + mi * 16 + l15) * 64 + kk * 32 + lg * 8];
      #pragma unroll
      for (int nj = 0; nj < 4; ++nj)
        bfr[nj] = *(const s16x8*)&Bs[(wc * 64 + nj * 16 + l15) * 64 + kk * 32 + lg * 8];
      #pragma unroll
      for (int mi = 0; mi < 4; ++mi)
        #pragma unroll
        for (int nj = 0; nj < 4; ++nj)
          acc[mi][nj] = MFMA_BF16(af[mi], bfr[nj], acc[mi][nj]);
    }
    __syncthreads();
  }

  #pragma unroll
  for (int mi = 0; mi < 4; ++mi) {
    const int mbase = brow + wr * 64 + mi * 16 + lg * 4;
    #pragma unroll
    for (int nj = 0; nj < 4; ++nj) {
      const int n = bcol + wc * 64 + nj * 16 + l15;
      const float bv = bias[n];
      #pragma unroll
      for (int r = 0; r < 4; ++r) {
        const int m = mbase + r;
        float val = acc[mi][nj][r] + bv;
        if (mode <= 1) {
          const float pv = __shfl_xor(val, 1);
          const int sp = m & (SEQ - 1);
          const int fi = (n >> 1) & 63;
          const float c = fcos[sp * 64 + fi];
          const float s = fsin[sp * 64 + fi];
          val = (n & 1) ? (pv * s + val * c) : (val * c - pv * s);
        }
        if (mode == 3) {
          ((float*)outv)[(size_t)m * DIM + n] = val;
        } else if (mode == 2) {
          const int b = m >> 11, sp = m & (SEQ - 1);
          const int h = n >> 7, d = n & (HD - 1);
          ((bf16*)outv)[((size_t)(b * NH + h) * HD + d) * SEQ + sp] = __float2bfloat16(val);
        } else {
          const int b = m >> 11, sp = m & (SEQ - 1);
          const int h = n >> 7, d = n & (HD - 1);
          ((bf16*)outv)[((size_t)(b * NH + h) * SEQ + sp) * HD + d] = __float2bfloat16(val);
        }
      }
    }
  }
}

// ---------------- causal flash attention, paired q-tiles, V^T input ----------------
// Q/K: (b,h,s,d) bf16.  V: (b,h,d,s) bf16 (pre-transposed by mode-2 GEMM).
// Block = (pair, bh): q-tiles A=pair, B=31-pair (33 compute-tiles -> balanced).
// LDS: Kl [t][d] swz (t&7)<<4 ; Vt [d][t] swz (d&7)<<4 ; Pl per-wave swz (q&7)<<4.
// 2 barriers/tile: B1 after staging, B3 after PV. Pl is same-wave only.
#define SOFTMAX_PHASE(sa, o, mrun, lrun, q0)                                   \
  {                                                                            \
    _Pragma("unroll")                                                          \
    for (int r = 0; r < 4; ++r) {                                              \
      const int q = (q0) + lg * 4 + r;                                         \
      float mx = -__builtin_inff();                                            \
      _Pragma("unroll")                                                        \
      for (int nj = 0; nj < 4; ++nj) {                                         \
        float v = sa[nj][r] * scale;                                           \
        if (diagM && (t0 + nj * 16 + l15 > q)) v = -__builtin_inff();          \
        sa[nj][r] = v;                                                         \
        mx = fmaxf(mx, v);                                                     \
      }                                                                        \
      _Pragma("unroll")                                                        \
      for (int off = 1; off < 16; off <<= 1) mx = fmaxf(mx, __shfl_xor(mx, off)); \
      const float mnew = fmaxf(mrun[r], mx);                                   \
      const float fsc = __expf(mrun[r] - mnew);                                \
      mrun[r] = mnew;                                                          \
      float rs = 0.f;                                                          \
      _Pragma("unroll")                                                        \
      for (int nj = 0; nj < 4; ++nj) {                                         \
        const float pp = __expf(sa[nj][r] - mnew);                             \
        sa[nj][r] = pp;                                                        \
        rs += pp;                                                              \
      }                                                                        \
      _Pragma("unroll")                                                        \
      for (int off = 1; off < 16; off <<= 1) rs += __shfl_xor(rs, off);        \
      lrun[r] = lrun[r] * fsc + rs;                                            \
      _Pragma("unroll")                                                        \
      for (int dj = 0; dj < 8; ++dj) o[dj][r] *= fsc;                          \
    }                                                                          \
  }

__global__ __launch_bounds__(256, 3)
void attn_fwd(const bf16* __restrict__ Q, const bf16* __restrict__ K,
              const bf16* __restrict__ V, bf16* __restrict__ ymat)
{
  __shared__ __align__(16) bf16 Kl[64 * 128];
  __shared__ __align__(16) bf16 Vt[128 * 64];
  __shared__ __align__(16) bf16 PlA[4 * 16 * 64];
  __shared__ __align__(16) bf16 PlB[4 * 16 * 64];
  const int tid = threadIdx.x, wid = tid >> 6, lane = tid & 63;
  const int l15 = lane & 15, lg = lane >> 4;
  const int pair = blockIdx.x, bh = blockIdx.y;
  const int qtA = pair, qtB = 31 - pair;
  const int b = bh >> 5, h = bh & 31;
  const bf16* Qb = Q + (size_t)bh * SEQ * HD;
  const bf16* Kb = K + (size_t)bh * SEQ * HD;
  const bf16* Vb = V + (size_t)bh * HD * SEQ;   // (d, s) layout
  const int q0A = qtA * 64 + wid * 16;
  const int q0B = qtB * 64 + wid * 16;

  s16x8 aqA[4], aqB[4];
  #pragma unroll
  for (int kk = 0; kk < 4; ++kk) {
    aqA[kk] = *(const s16x8*)&Qb[(size_t)(q0A + l15) * HD + kk * 32 + lg * 8];
    aqB[kk] = *(const s16x8*)&Qb[(size_t)(q0B + l15) * HD + kk * 32 + lg * 8];
  }

  fx4 oA[8] = {}, oB[8] = {};
  float mA[4], lA[4], mB[4], lB[4];
  #pragma unroll
  for (int r = 0; r < 4; ++r) {
    mA[r] = -__builtin_inff(); lA[r] = 0.f;
    mB[r] = -__builtin_inff(); lB[r] = 0.f;
  }
  const float scale = 0.08838834764831845f;

  for (int kt = 0; kt <= qtB; ++kt) {
    const int t0 = kt * 64;
    const bool doA = (kt <= qtA);     // block-uniform

    // stage K rows [t][d] and V^T rows [d][t] (pre-swizzled source -> linear LDS)
    #pragma unroll
    for (int i = 0; i < 4; ++i) {
      const int chunk = i * 4 + wid;                  // wave-uniform 0..15
      // K: 4 rows of 256B per chunk
      const int trow = chunk * 4 + lg;
      const int kcol = ((l15 ^ (trow & 7)) * 8);
      gload16(Kb + (size_t)(t0 + trow) * HD + kcol, Kl + chunk * 512);
      // V^T: 8 rows of 128B per chunk
      const int d = chunk * 8 + (lane >> 3);
      const int tcol = ((lane & 7) ^ (d & 7)) * 8;
      gload16(Vb + (size_t)d * SEQ + t0 + tcol, Vt + chunk * 512);
    }
    __syncthreads();   // B1

    // QK^T: shared Kl fragments feed both q-sets
    fx4 sA[4], sB[4];
    __builtin_amdgcn_s_setprio(1);
    #pragma unroll
    for (int nj = 0; nj < 4; ++nj) {
      fx4 sa = {}, sb = {};
      #pragma unroll
      for (int kk = 0; kk < 4; ++kk) {
        const int trow = nj * 16 + l15;
        const int colp = (kk * 32 + lg * 8) ^ ((trow & 7) << 3);
        s16x8 bk = *(const s16x8*)&Kl[trow * HD + colp];
        sb = MFMA_BF16(aqB[kk], bk, sb);
        if (doA) sa = MFMA_BF16(aqA[kk], bk, sa);
      }
      sB[nj] = sb; sA[nj] = sa;
    }
    __builtin_amdgcn_s_setprio(0);

    // softmax + P writes (per-wave Pl regions; same-wave dependency only)
    {
      const bool diagM = (kt == qtB);
      SOFTMAX_PHASE(sB, oB, mB, lB, q0B)
      #pragma unroll
      for (int r = 0; r < 4; ++r) {
        const int row = lg * 4 + r;
        #pragma unroll
        for (int nj = 0; nj < 4; ++nj) {
          const int colp = (nj * 16 + l15) ^ ((row & 7) << 3);
          PlB[wid * 1024 + row * 64 + colp] = __float2bfloat16(sB[nj][r]);
        }
      }
    }
    if (doA) {
      const bool diagM = (kt == qtA);
      SOFTMAX_PHASE(sA, oA, mA, lA, q0A)
      #pragma unroll
      for (int r = 0; r < 4; ++r) {
        const int row = lg * 4 + r;
        #pragma unroll
        for (int nj = 0; nj < 4; ++nj) {
          const int colp = (nj * 16 + l15) ^ ((row & 7) << 3);
          PlA[wid * 1024 + row * 64 + colp] = __float2bfloat16(sA[nj][r]);
        }
      }
    }

    // PV: shared Vt fragments feed both q-sets
    s16x8 paA[2], paB[2];
    #pragma unroll
    for (int k2 = 0; k2 < 2; ++k2) {
      const int colp = (k2 * 32 + lg * 8) ^ ((l15 & 7) << 3);
      paB[k2] = *(const s16x8*)&PlB[wid * 1024 + l15 * 64 + colp];
      if (doA) paA[k2] = *(const s16x8*)&PlA[wid * 1024 + l15 * 64 + colp];
    }
    __builtin_amdgcn_s_setprio(1);
    #pragma unroll
    for (int dj = 0; dj < 8; ++dj) {
      const int d = dj * 16 + l15;
      #pragma unroll
      for (int k2 = 0; k2 < 2; ++k2) {
        const int colp = (k2 * 32 + lg * 8) ^ ((d & 7) << 3);
        s16x8 bv = *(const s16x8*)&Vt[d * 64 + colp];
        oB[dj] = MFMA_BF16(paB[k2], bv, oB[dj]);
        if (doA) oA[dj] = MFMA_BF16(paA[k2], bv, oA[dj]);
      }
    }
    __builtin_amdgcn_s_setprio(0);
    __syncthreads();   // B3: safe to overwrite Kl/Vt next iter
  }

  // epilogue: both q-sets, scrambled ymat layout
  #pragma unroll
  for (int dj = 0; dj < 8; ++dj) {
    #pragma unroll
    for (int r = 0; r < 4; ++r) {
      const int d = dj * 16 + l15;
      const int u = h * HD + d;
      const size_t rowbase = ((size_t)(b * SEQ + (u >> 1))) * DIM + ((u & 1) << 11);
      ymat[rowbase + q0A + lg * 4 + r] = __float2bfloat16(oA[dj][r] / lA[r]);
      ymat[rowbase + q0B + lg * 4 + r] = __float2bfloat16(oB[dj][r] / lB[r]);
    }
  }
}

extern "C" void kernel_launch(void* const* d_in, const int* in_sizes, int n_in,
                              void* d_out, int out_size, void* d_ws, size_t ws_size,
                              hipStream_t stream)
{
  (void)in_sizes; (void)n_in; (void)out_size;
  const float* x  = (const float*)d_in[0];
  const float* wq = (const float*)d_in[1];
  const float* bq = (const float*)d_in[2];
  const float* wk = (const float*)d_in[3];
  const float* bk = (const float*)d_in[4];
  const float* wv = (const float*)d_in[5];
  const float* bv = (const float*)d_in[6];
  const float* wo = (const float*)d_in[7];
  const float* bo = (const float*)d_in[8];
  const float* fc = (const float*)d_in[9];
  const float* fs = (const float*)d_in[10];

  const size_t NE = (size_t)2 * SEQ * DIM;
  const size_t NW = (size_t)DIM * DIM;
  const size_t SLOT = NE * sizeof(bf16);
  const size_t NEED_FAST = 6 * SLOT + 256;
  const size_t NEED_SLOW = 4 * SLOT + 256;

  dim3 blk(256), gg(32, 32);
  if (ws_size >= NEED_FAST) {
    bf16* xb = (bf16*)((char*)d_ws + 256);
    bf16* wb = xb + NE;
    bf16* qb = wb + NW;
    bf16* kb = qb + NE;
    bf16* vb = kb + NE;
    bf16* ym = vb + NE;
    const int n8x = (int)(NE / 8), n8w = (int)(NW / 8);
    dim3 cg(2048);
    hipLaunchKernelGGL(cvt_f32_bf16, cg, blk, 0, stream, x, xb, n8x);
    hipLaunchKernelGGL(cvt_f32_bf16, cg, blk, 0, stream, wq, wb, n8w);
    hipLaunchKernelGGL(gemm_fast, gg, blk, 0, stream, xb, wb, bq, fc, fs, qb, 0);
    hipLaunchKernelGGL(cvt_f32_bf16, cg, blk, 0, stream, wk, wb, n8w);
    hipLaunchKernelGGL(gemm_fast, gg, blk, 0, stream, xb, wb, bk, fc, fs, kb, 1);
    hipLaunchKernelGGL(cvt_f32_bf16, cg, blk, 0, stream, wv, wb, n8w);
    hipLaunchKernelGGL(gemm_fast, gg, blk, 0, stream, xb, wb, bv, fc, fs, vb, 2);
    hipLaunchKernelGGL(attn_fwd, dim3(16, 64), blk, 0, stream, qb, kb, vb, ym);
    hipLaunchKernelGGL(cvt_f32_bf16, cg, blk, 0, stream, wo, wb, n8w);
    hipLaunchKernelGGL(gemm_fast, gg, blk, 0, stream, ym, wb, bo, fc, fs, d_out, 3);
  } else if (ws_size >= NEED_SLOW) {
    bf16* qb = (bf16*)((char*)d_ws + 256);
    bf16* kb = qb + NE;
    bf16* vb = kb + NE;
    bf16* ym = vb + NE;
    hipLaunchKernelGGL(gemm_slow, gg, blk, 0, stream, x, wq, bq, fc, fs, qb, 0);
    hipLaunchKernelGGL(gemm_slow, gg, blk, 0, stream, x, wk, bk, fc, fs, kb, 1);
    hipLaunchKernelGGL(gemm_slow, gg, blk, 0, stream, x, wv, bv, fc, fs, vb, 2);
    hipLaunchKernelGGL(attn_fwd, dim3(16, 64), blk, 0, stream, qb, kb, vb, ym);
    hipLaunchKernelGGL(gemm_slow, gg, blk, 0, stream, ym, wo, bo, fc, fs, d_out, 3);
  }
}